// Round 15
// baseline (239.723 us; speedup 1.0000x reference)
//
#include <hip/hip_runtime.h>
#include <math.h>

#define NB 32    // batch
#define NS 128   // steps
#define NI 256   // in_dim
#define NC 128   // num capsules
#define ND 64    // dim capsule

#define L4 9.210340371976184f  // ln(10000)

// ---------------------------------------------------------------------------
// k_prep:
//   blocks [0,1024):      M[b,s,d] = sum_i u*W ; U[b,s] = sum_i u
//   blocks [1024,1056):   PE1[n][d]
// ---------------------------------------------------------------------------
__global__ __launch_bounds__(256) void k_prep(const float* __restrict__ u,
                                              const float* __restrict__ W,
                                              float* __restrict__ M,
                                              float* __restrict__ U,
                                              float* __restrict__ PE1) {
    int blk = blockIdx.x;
    int t = threadIdx.x;
    if (blk < 1024) {
        int row = blk * 4 + (t >> 6);   // b*NS + s
        int d = t & 63;
        const float* ur = u + row * NI;
        float acc = 0.f, rs = 0.f;
#pragma unroll 4
        for (int i = 0; i < NI; ++i) {
            float v = ur[i];
            acc = fmaf(v, W[i * ND + d], acc);
            rs += v;
        }
        M[row * ND + d] = acc;
        if (d == 0) U[row] = rs;
    } else {
        int idx = (blk - 1024) * 256 + t;   // 8192 elems, [n][d]
        int n = idx >> 6, d = idx & 63;
        float ang = (float)n * __expf(-L4 * (float)(d >> 1) * (1.f / 32.f));
        float sv, cv;
        __sincosf(ang, &sv, &cv);
        PE1[idx] = (d & 1) ? cv : sv;
    }
}

// ---------------------------------------------------------------------------
// kR v10: routing iteration with IN-STAGING SOFTMAX (kS deleted, 4 launches).
// Block = (b-pair, n), 256 thr, ~21 KB LDS, grid 2048, launch_bounds(256,4).
// Logits live TRANSPOSED: bl[b][s][n] (pass 2 writes scattered dwords, ~32MB
// L2 traffic). Staging: thread (bh, s) reads its row bl[b][s][0..127]
// (512 B contiguous, L2-resident), computes an EXACT max-subtracted softmax
// in-registers (2 passes, L1-hot reread; 128 native v_exp), takes the
// block's own n -> c. 128x block redundancy costs ~1 us grid-wide; zero
// atomics, zero NaN risk. bl double-buffered across iterations (blr/blw).
//   pass 1: u-hat = M + pe2(rotation) in registers (retained); acc += c*uh;
//           shfl+LDS reduce; 32-lane tail: +pe1*T2, squash, PUu.
//   pass 2: dot(uh, outs4) -> red2[s*17+dq]; 256 thr sum 16 partials
//           + PUu*U -> blw[b][s][n].
// ---------------------------------------------------------------------------
__global__ __launch_bounds__(256, 4) void kR(const float* __restrict__ M,
                                             const float* __restrict__ U,
                                             const float* __restrict__ PE1,
                                             const float* __restrict__ mask,
                                             const float* __restrict__ blr,
                                             float* __restrict__ blw,
                                             float* __restrict__ og,
                                             int first, int last) {
    int bp = blockIdx.x;                // (b-pair)*128 + n
    int n  = bp & 127;
    int b0 = (bp >> 7) * 2;
    int t  = threadIdx.x;

    __shared__ float  cs[2][NS];        // 1 KB
    __shared__ float4 redw[2][4][16];   // 2 KB
    __shared__ float4 outs4[2][16];     // 512 B
    __shared__ float  tpar[2][2];
    __shared__ float  sc2[2][2];        // [bh][{scale, PUu}]
    __shared__ float  red2[2][NS * 17]; // 17408 B

    // ---- staging: per-thread exact softmax over own (b,s) row ----
    {
        int bh = t >> 7, s = t & 127;
        int b = b0 + bh;
        float uu = U[b * NS + s];
        float cv;
        if (first) {
            cv = mask[b * NS + s];      // /128 folded into squash
        } else {
            const float4* row = (const float4*)(blr + ((size_t)(b * NS + s)) * NC);
            float mx = -1e30f;
#pragma unroll 8
            for (int i = 0; i < 32; ++i) {
                float4 v = row[i];
                mx = fmaxf(mx, fmaxf(fmaxf(v.x, v.y), fmaxf(v.z, v.w)));
            }
            float den = 0.f;
#pragma unroll 8
            for (int i = 0; i < 32; ++i) {
                float4 v = row[i];      // L1-hot reread
                den += __expf(v.x - mx) + __expf(v.y - mx) +
                       __expf(v.z - mx) + __expf(v.w - mx);
            }
            float blv = blr[((size_t)(b * NS + s)) * NC + n];
            cv = __expf(blv - mx) * mask[b * NS + s] / den;
        }
        cs[bh][s] = cv;
        float p = cv * uu;
#pragma unroll
        for (int o = 32; o > 0; o >>= 1) p += __shfl_xor(p, o);
        if ((t & 63) == 0) tpar[bh][(t >> 6) & 1] = p;
    }

    int dq = t & 15, sq = t >> 4;
    int s0 = sq * 8;
    // pe2 frequencies for (n, dq) — shared by both batches
    int k2 = n * 32 + dq * 2;
    float g0 = __expf(-L4 * (float)k2 * (1.f / 4096.f));
    float g1 = __expf(-L4 * (float)(k2 + 1) * (1.f / 4096.f));
    float sg0 = __sinf(g0), cg0 = __cosf(g0);
    float sg1 = __sinf(g1), cg1 = __cosf(g1);
    float sa = __sinf((float)s0 * g0), ca = __cosf((float)s0 * g0);
    float sb = __sinf((float)s0 * g1), cb = __cosf((float)s0 * g1);
    __syncthreads();

    // ---- pass 1: u-hat in registers (retained), acc += c*uh ----
    const float4* M4a = (const float4*)(M + (size_t)(b0 * NS) * ND) + dq;
    const float4* M4b = M4a + NS * 16;
    float4 va[8], vb[8];
    float4 acc0 = make_float4(0.f, 0.f, 0.f, 0.f);
    float4 acc1 = make_float4(0.f, 0.f, 0.f, 0.f);
#pragma unroll
    for (int i = 0; i < 8; ++i) {
        int s = s0 + i;
        float4 m0 = M4a[s * 16];
        float4 m1 = M4b[s * 16];
        float cc0 = cs[0][s], cc1 = cs[1][s];
        float4 u0, u1;
        u0.x = m0.x + sa; u0.y = m0.y + ca; u0.z = m0.z + sb; u0.w = m0.w + cb;
        u1.x = m1.x + sa; u1.y = m1.y + ca; u1.z = m1.z + sb; u1.w = m1.w + cb;
        va[i] = u0; vb[i] = u1;
        acc0.x = fmaf(cc0, u0.x, acc0.x);
        acc0.y = fmaf(cc0, u0.y, acc0.y);
        acc0.z = fmaf(cc0, u0.z, acc0.z);
        acc0.w = fmaf(cc0, u0.w, acc0.w);
        acc1.x = fmaf(cc1, u1.x, acc1.x);
        acc1.y = fmaf(cc1, u1.y, acc1.y);
        acc1.z = fmaf(cc1, u1.z, acc1.z);
        acc1.w = fmaf(cc1, u1.w, acc1.w);
        float nsa = fmaf(sa, cg0, ca * sg0);
        float nca = fmaf(ca, cg0, -sa * sg0);
        sa = nsa; ca = nca;
        float nsb = fmaf(sb, cg1, cb * sg1);
        float ncb = fmaf(cb, cg1, -sb * sg1);
        sb = nsb; cb = ncb;
    }
    // reduce the 4 sq-chunks within each wave (lanes xor 16, 32)
#pragma unroll
    for (int o = 16; o <= 32; o <<= 1) {
        acc0.x += __shfl_xor(acc0.x, o); acc0.y += __shfl_xor(acc0.y, o);
        acc0.z += __shfl_xor(acc0.z, o); acc0.w += __shfl_xor(acc0.w, o);
        acc1.x += __shfl_xor(acc1.x, o); acc1.y += __shfl_xor(acc1.y, o);
        acc1.z += __shfl_xor(acc1.z, o); acc1.w += __shfl_xor(acc1.w, o);
    }
    if ((t & 48) == 0) {
        int w = t >> 6;
        redw[0][w][dq] = acc0;
        redw[1][w][dq] = acc1;
    }
    __syncthreads();

    // ---- combine + squash (lanes 0-31: 16 lanes per bh) ----
    if (t < 32) {
        int bh = t >> 4, q = t & 15;
        float4 r0 = redw[bh][0][q], r1 = redw[bh][1][q];
        float4 r2 = redw[bh][2][q], r3 = redw[bh][3][q];
        float4 o;
        o.x = r0.x + r1.x + r2.x + r3.x;
        o.y = r0.y + r1.y + r2.y + r3.y;
        o.z = r0.z + r1.z + r2.z + r3.z;
        o.w = r0.w + r1.w + r2.w + r3.w;
        float T2 = tpar[bh][0] + tpar[bh][1];
        float4 p14 = ((const float4*)PE1)[n * 16 + q];
        o.x = fmaf(p14.x, T2, o.x);
        o.y = fmaf(p14.y, T2, o.y);
        o.z = fmaf(p14.z, T2, o.z);
        o.w = fmaf(p14.w, T2, o.w);
        if (first) { o.x *= (1.f / 128.f); o.y *= (1.f / 128.f);
                     o.z *= (1.f / 128.f); o.w *= (1.f / 128.f); }
        outs4[bh][q] = o;
        float ssq = o.x * o.x + o.y * o.y + o.z * o.z + o.w * o.w;
        float ppu = o.x * p14.x + o.y * p14.y + o.z * p14.z + o.w * p14.w;
#pragma unroll
        for (int o2 = 1; o2 <= 8; o2 <<= 1) {   // within 16-lane group
            ssq += __shfl_xor(ssq, o2);
            ppu += __shfl_xor(ppu, o2);
        }
        if (q == 0) {
            sc2[bh][0] = ssq / (1.f + ssq) * rsqrtf(ssq + 1e-7f);
            sc2[bh][1] = ppu;
        }
    }
    __syncthreads();

    if (last) {
        if (t < 32) {
            int bh = t >> 4, q = t & 15;
            float sc = sc2[bh][0];
            float4 o = outs4[bh][q];
            o.x *= sc; o.y *= sc; o.z *= sc; o.w *= sc;
            ((float4*)og)[((b0 + bh) * NC + n) * 16 + q] = o;
        }
        return;
    }

    // ---- pass 2: dot retained u-hat with outs4, LDS partial, reduce ----
    float4 oa = outs4[0][dq], ob = outs4[1][dq];
#pragma unroll
    for (int i = 0; i < 8; ++i) {
        int s = s0 + i;
        float4 v0 = va[i], v1 = vb[i];
        red2[0][s * 17 + dq] = v0.x * oa.x + v0.y * oa.y + v0.z * oa.z + v0.w * oa.w;
        red2[1][s * 17 + dq] = v1.x * ob.x + v1.y * ob.y + v1.z * ob.z + v1.w * ob.w;
    }
    __syncthreads();
    {
        int bh = t >> 7, s = t & 127;
        int b = b0 + bh;
        const float* r = &red2[bh][s * 17];
        float sum = 0.f;
#pragma unroll
        for (int q = 0; q < 16; ++q) sum += r[q];
        // transposed store: bl[b][s][n] (scattered dwords, L2-resident)
        blw[((size_t)(b * NS + s)) * NC + n] =
            sc2[bh][0] * (sum + sc2[bh][1] * U[b * NS + s]);
    }
}

// ---------------------------------------------------------------------------
extern "C" void kernel_launch(void* const* d_in, const int* in_sizes, int n_in,
                              void* d_out, int out_size, void* d_ws, size_t ws_size,
                              hipStream_t stream) {
    const float* u    = (const float*)d_in[0];  // (32,128,256)
    const float* mask = (const float*)d_in[1];  // (32,128)
    const float* W    = (const float*)d_in[2];  // (1,256,64)
    float* out = (float*)d_out;                 // (32,128,64) = [b][n][d]

    float* ws  = (float*)d_ws;
    float* M   = ws;                            // 262144
    float* U   = M + NB * NS * ND;              // 4096
    float* PE1 = U + NB * NS;                   // 8192
    float* bl0 = PE1 + NC * ND;                 // 524288  [b][s][n]
    float* bl1 = bl0 + NB * NS * NC;            // 524288  [b][s][n]

    k_prep<<<1056, 256, 0, stream>>>(u, W, M, U, PE1);

    // iter 0 (c = mask/128) -> bl0
    kR<<<2048, 256, 0, stream>>>(M, U, PE1, mask, bl1, bl0, out, 1, 0);
    // iter 1 (softmax of bl0 in staging) -> bl1
    kR<<<2048, 256, 0, stream>>>(M, U, PE1, mask, bl0, bl1, out, 0, 0);
    // iter 2 (softmax of bl1 in staging, final) -> d_out
    kR<<<2048, 256, 0, stream>>>(M, U, PE1, mask, bl1, bl0, out, 0, 1);
}